// Round 2
// baseline (1239.687 us; speedup 1.0000x reference)
//
#include <hip/hip_runtime.h>
#include <hip/hip_bf16.h>

#define NN 500000
// H1=256, H2=128, H3=64; E=128

typedef unsigned short ushort_t;
typedef __attribute__((ext_vector_type(8))) __bf16 bf16x8;
typedef __attribute__((ext_vector_type(2))) __bf16 bf16x2;
typedef __attribute__((ext_vector_type(4))) float f32x4;

__device__ inline ushort_t f2bf(float f) {
  union { float f; unsigned u; } x; x.f = f;
  return (ushort_t)((x.u + 0x7FFFu + ((x.u >> 16) & 1u)) >> 16);
}
__device__ inline float lrelu(float v) { return fmaxf(v, 0.f) + 0.01f * fminf(v, 0.f); }
__device__ inline unsigned pk2(float lo, float hi) {
  union { bf16x2 v; unsigned u; } x; x.v[0] = (__bf16)lo; x.v[1] = (__bf16)hi; return x.u;
}
#define SHF(v, s) ((unsigned)__shfl((int)(v), (s), 64))

// ---------------- K_colmax: masked per-column max over N rows ----------------
__global__ __launch_bounds__(256) void k_colmax(
    const float* __restrict__ enc, const int* __restrict__ cs,
    float* mu_in, float* mu_not)
{
  __shared__ float4 s_in[256], s_not[256];
  const int tid = threadIdx.x;
  const int c4 = tid & 31;    // float4-column 0..31
  const int rs = tid >> 5;    // row slice 0..7
  const long base = (long)blockIdx.x * 256;
  float4 mi = {0.f, 0.f, 0.f, 0.f}, mn = {0.f, 0.f, 0.f, 0.f};
  const float4* e4 = (const float4*)enc;
  #pragma unroll 4
  for (int it = 0; it < 32; ++it) {
    long r = base + rs + 8L * it;
    if (r < NN) {
      float4 v = e4[r * 32 + c4];
      bool ins = cs[r] > 0;
      mi.x = fmaxf(mi.x, ins ? v.x : 0.f); mi.y = fmaxf(mi.y, ins ? v.y : 0.f);
      mi.z = fmaxf(mi.z, ins ? v.z : 0.f); mi.w = fmaxf(mi.w, ins ? v.w : 0.f);
      mn.x = fmaxf(mn.x, ins ? 0.f : v.x); mn.y = fmaxf(mn.y, ins ? 0.f : v.y);
      mn.z = fmaxf(mn.z, ins ? 0.f : v.z); mn.w = fmaxf(mn.w, ins ? 0.f : v.w);
    }
  }
  s_in[tid] = mi; s_not[tid] = mn;
  __syncthreads();
  if (tid < 32) {
    for (int j = 1; j < 8; ++j) {
      float4 a = s_in[j * 32 + tid], b = s_not[j * 32 + tid];
      mi.x = fmaxf(mi.x, a.x); mi.y = fmaxf(mi.y, a.y);
      mi.z = fmaxf(mi.z, a.z); mi.w = fmaxf(mi.w, a.w);
      mn.x = fmaxf(mn.x, b.x); mn.y = fmaxf(mn.y, b.y);
      mn.z = fmaxf(mn.z, b.z); mn.w = fmaxf(mn.w, b.w);
    }
    // maxima are >= 0 so int-bit compare == float compare
    atomicMax((int*)&mu_in[4 * tid + 0], __float_as_int(mi.x));
    atomicMax((int*)&mu_in[4 * tid + 1], __float_as_int(mi.y));
    atomicMax((int*)&mu_in[4 * tid + 2], __float_as_int(mi.z));
    atomicMax((int*)&mu_in[4 * tid + 3], __float_as_int(mi.w));
    atomicMax((int*)&mu_not[4 * tid + 0], __float_as_int(mn.x));
    atomicMax((int*)&mu_not[4 * tid + 1], __float_as_int(mn.y));
    atomicMax((int*)&mu_not[4 * tid + 2], __float_as_int(mn.z));
    atomicMax((int*)&mu_not[4 * tid + 3], __float_as_int(mn.w));
  }
}

// ---------------- K_cvec: fold mu through W1 rows 0..255 + b1 into c[256] ----------------
__global__ __launch_bounds__(512) void k_cvec(
    const float* __restrict__ W1, const float* __restrict__ b1,
    const float* __restrict__ mu_in, const float* __restrict__ mu_not,
    float* __restrict__ cvec)
{
  __shared__ float tmp[512];
  const int tid = threadIdx.x;
  const int j = tid & 255, h = tid >> 8;
  float c = h ? 0.f : b1[j];
  #pragma unroll 8
  for (int e = 64 * h; e < 64 * h + 64; ++e) {
    c += mu_in[e]  * W1[e * 256 + j];
    c += mu_not[e] * W1[(128 + e) * 256 + j];
  }
  tmp[tid] = c;
  __syncthreads();
  if (tid < 256) cvec[tid] = tmp[tid] + tmp[tid + 256];
}

// ---------------- K_mlp: persistent, all weights LDS-resident, barrier-free loop ----------
// Orientation: A = weights [n_out][k] (LDS), B = activations^T (row index in n slot).
// Layer handoff = 4-lane butterfly shuffles (no LDS bounce, no __syncthreads in loop).
__global__ __launch_bounds__(512, 1) void k_mlp(
    const float* __restrict__ enc,
    const float* __restrict__ W1, const float* __restrict__ W2,
    const float* __restrict__ W3,
    const float* __restrict__ cvec, const float* __restrict__ b2,
    const float* __restrict__ b3, const float* __restrict__ W4,
    const float* __restrict__ b4,
    float* __restrict__ eL, float* __restrict__ psum)
{
  __shared__ ushort_t sW1[256 * 136];   // [n1][k=e]   69632 B
  __shared__ ushort_t sW2[128 * 264];   // [n2][k=n1]  67584 B
  __shared__ ushort_t sW3[64 * 136];    // [n3][k=n2]  17408 B
  __shared__ float sC[520];             // c[256]|b2[128]|b3[64]|W4[64]|b4

  const int tid = threadIdx.x;

  // ---- one-time staging: fp32 global -> bf16 LDS (transposed) ----
  for (int idx = tid; idx < 32768; idx += 512) {
    int n = idx & 255, k = idx >> 8;              // n1, e
    sW1[n * 136 + k] = f2bf(W1[(256 + k) * 256 + n]);
  }
  for (int idx = tid; idx < 32768; idx += 512) {
    int n = idx & 127, k = idx >> 7;              // n2, n1
    sW2[n * 264 + k] = f2bf(W2[k * 128 + n]);
  }
  for (int idx = tid; idx < 8192; idx += 512) {
    int n = idx & 63, k = idx >> 6;               // n3, n2
    sW3[n * 136 + k] = f2bf(W3[k * 64 + n]);
  }
  if (tid < 256) sC[tid] = cvec[tid];
  else if (tid < 384) sC[tid] = b2[tid - 256];
  else if (tid < 448) sC[tid] = b3[tid - 384];
  else sC[tid] = W4[tid - 448];
  if (tid == 0) sC[512] = b4[0];
  __syncthreads();   // the ONLY block-wide barrier

  const int wave = tid >> 6, lane = tid & 63;
  const int lr = lane & 15, lg = lane >> 4;
  const int wid = blockIdx.x * 8 + wave;          // 0..2047
  const int selhi = lane & 32;                    // lg>>1 flag
  const int srcLo = lr + ((lane & 16) << 1);      // partner lanes for butterfly
  const int srcHi = srcLo + 16;

  const ushort_t* w1p = sW1 + lr * 136 + 8 * lg;  // + mt*2176 + kt*32
  const ushort_t* w2p = sW2 + lr * 264 + 8 * lg;  // + mt*4224 + kt*32
  const ushort_t* w3p = sW3 + lr * 136 + 8 * lg;

  float es = 0.f;

  // preload first row-group (row = r0 + lr; this wave's partition is exact, no tail)
  float4 cA[8];
  {
    const float4* p = (const float4*)(enc + (size_t)(wid * 16 + lr) * 128);
    #pragma unroll
    for (int kt = 0; kt < 4; ++kt) {
      cA[2 * kt]     = p[kt * 8 + lg * 2];
      cA[2 * kt + 1] = p[kt * 8 + lg * 2 + 1];
    }
  }

  for (int r0 = wid * 16; r0 < NN; r0 += 32768) {
    // ---- prefetch next row-group ----
    int rn = r0 + 32768; if (rn >= NN) rn = r0;   // last iter: dummy (unused)
    float4 nA[8];
    {
      const float4* p = (const float4*)(enc + (size_t)(rn + lr) * 128);
      #pragma unroll
      for (int kt = 0; kt < 4; ++kt) {
        nA[2 * kt]     = p[kt * 8 + lg * 2];
        nA[2 * kt + 1] = p[kt * 8 + lg * 2 + 1];
      }
    }
    // ---- B1 frags: lane holds row (r0+lr), feats 32kt+8lg..+7 ----
    bf16x8 B1[4];
    #pragma unroll
    for (int kt = 0; kt < 4; ++kt) {
      float4 f0 = cA[2 * kt], f1 = cA[2 * kt + 1];
      bf16x8 b;
      b[0] = (__bf16)f0.x; b[1] = (__bf16)f0.y; b[2] = (__bf16)f0.z; b[3] = (__bf16)f0.w;
      b[4] = (__bf16)f1.x; b[5] = (__bf16)f1.y; b[6] = (__bf16)f1.z; b[7] = (__bf16)f1.w;
      B1[kt] = b;
    }
    // ---- L1: D[n1][row], n1 tiles of 16 ----
    f32x4 acc[16];
    #pragma unroll
    for (int mt = 0; mt < 16; ++mt) acc[mt] = (f32x4){0.f, 0.f, 0.f, 0.f};
    #pragma unroll
    for (int mt = 0; mt < 16; ++mt) {
      #pragma unroll
      for (int kt = 0; kt < 4; ++kt) {
        bf16x8 a = *(const bf16x8*)(w1p + mt * 2176 + kt * 32);
        acc[mt] = __builtin_amdgcn_mfma_f32_16x16x32_bf16(a, B1[kt], acc[mt], 0, 0, 0);
      }
    }
    // ---- L1 epilogue: +c, lrelu, pack; lane holds h1[n1=16t+4lg+j] ----
    unsigned q1[32];
    #pragma unroll
    for (int mt = 0; mt < 16; ++mt) {
      float4 cb = *(const float4*)(sC + 16 * mt + 4 * lg);
      float v0 = lrelu(acc[mt][0] + cb.x), v1 = lrelu(acc[mt][1] + cb.y);
      float v2 = lrelu(acc[mt][2] + cb.z), v3 = lrelu(acc[mt][3] + cb.w);
      q1[2 * mt] = pk2(v0, v1); q1[2 * mt + 1] = pk2(v2, v3);
    }
    // ---- butterfly: build B2[kt] (k = n1 = 32kt+8lg+i) ----
    bf16x8 B2[8];
    #pragma unroll
    for (int kt = 0; kt < 8; ++kt) {
      unsigned w0a = SHF(q1[4 * kt + 0], srcLo), w0b = SHF(q1[4 * kt + 2], srcLo);
      unsigned w1a = SHF(q1[4 * kt + 1], srcLo), w1b = SHF(q1[4 * kt + 3], srcLo);
      unsigned w2a = SHF(q1[4 * kt + 0], srcHi), w2b = SHF(q1[4 * kt + 2], srcHi);
      unsigned w3a = SHF(q1[4 * kt + 1], srcHi), w3b = SHF(q1[4 * kt + 3], srcHi);
      union { unsigned w[4]; bf16x8 v; } u;
      u.w[0] = selhi ? w0b : w0a; u.w[1] = selhi ? w1b : w1a;
      u.w[2] = selhi ? w2b : w2a; u.w[3] = selhi ? w3b : w3a;
      B2[kt] = u.v;
    }
    // ---- L2 ----
    f32x4 acc2[8];
    #pragma unroll
    for (int mt = 0; mt < 8; ++mt) acc2[mt] = (f32x4){0.f, 0.f, 0.f, 0.f};
    #pragma unroll
    for (int mt = 0; mt < 8; ++mt) {
      #pragma unroll
      for (int kt = 0; kt < 8; ++kt) {
        bf16x8 a = *(const bf16x8*)(w2p + mt * 4224 + kt * 32);
        acc2[mt] = __builtin_amdgcn_mfma_f32_16x16x32_bf16(a, B2[kt], acc2[mt], 0, 0, 0);
      }
    }
    unsigned q2[16];
    #pragma unroll
    for (int mt = 0; mt < 8; ++mt) {
      float4 cb = *(const float4*)(sC + 256 + 16 * mt + 4 * lg);
      float v0 = lrelu(acc2[mt][0] + cb.x), v1 = lrelu(acc2[mt][1] + cb.y);
      float v2 = lrelu(acc2[mt][2] + cb.z), v3 = lrelu(acc2[mt][3] + cb.w);
      q2[2 * mt] = pk2(v0, v1); q2[2 * mt + 1] = pk2(v2, v3);
    }
    // ---- butterfly: B3[kt] (k = n2 = 32kt+8lg+i) ----
    bf16x8 B3[4];
    #pragma unroll
    for (int kt = 0; kt < 4; ++kt) {
      unsigned w0a = SHF(q2[4 * kt + 0], srcLo), w0b = SHF(q2[4 * kt + 2], srcLo);
      unsigned w1a = SHF(q2[4 * kt + 1], srcLo), w1b = SHF(q2[4 * kt + 3], srcLo);
      unsigned w2a = SHF(q2[4 * kt + 0], srcHi), w2b = SHF(q2[4 * kt + 2], srcHi);
      unsigned w3a = SHF(q2[4 * kt + 1], srcHi), w3b = SHF(q2[4 * kt + 3], srcHi);
      union { unsigned w[4]; bf16x8 v; } u;
      u.w[0] = selhi ? w0b : w0a; u.w[1] = selhi ? w1b : w1a;
      u.w[2] = selhi ? w2b : w2a; u.w[3] = selhi ? w3b : w3a;
      B3[kt] = u.v;
    }
    // ---- L3 ----
    f32x4 acc3[4];
    #pragma unroll
    for (int mt = 0; mt < 4; ++mt) acc3[mt] = (f32x4){0.f, 0.f, 0.f, 0.f};
    #pragma unroll
    for (int mt = 0; mt < 4; ++mt) {
      #pragma unroll
      for (int kt = 0; kt < 4; ++kt) {
        bf16x8 a = *(const bf16x8*)(w3p + mt * 2176 + kt * 32);
        acc3[mt] = __builtin_amdgcn_mfma_f32_16x16x32_bf16(a, B3[kt], acc3[mt], 0, 0, 0);
      }
    }
    // ---- L4: +b3, lrelu, dot W4, reduce over lg ----
    float dot = 0.f;
    #pragma unroll
    for (int t = 0; t < 4; ++t) {
      float4 cb  = *(const float4*)(sC + 384 + 16 * t + 4 * lg);
      float4 w4v = *(const float4*)(sC + 448 + 16 * t + 4 * lg);
      dot += lrelu(acc3[t][0] + cb.x) * w4v.x + lrelu(acc3[t][1] + cb.y) * w4v.y
           + lrelu(acc3[t][2] + cb.z) * w4v.z + lrelu(acc3[t][3] + cb.w) * w4v.w;
    }
    dot += __shfl_xor(dot, 16, 64);
    dot += __shfl_xor(dot, 32, 64);
    float ev = expf(dot + sC[512]);
    if (lg == 0) eL[r0 + lr] = ev;
    es += ev;                      // every lane (4x duplication, fixed below)
    #pragma unroll
    for (int i = 0; i < 8; ++i) cA[i] = nA[i];
  }
  // wave-wide partial softmax denominator (deterministic: one slot per wave)
  #pragma unroll
  for (int off = 1; off < 64; off <<= 1) es += __shfl_xor(es, off, 64);
  if (lane == 0) psum[wid] = 0.25f * es;
}

// ---------------- final reduce + normalize ----------------
__global__ __launch_bounds__(256) void k_finalsum(const float* __restrict__ psum,
                                                  float* __restrict__ scal)
{
  const int tid = threadIdx.x;
  float s = 0.f;
  #pragma unroll
  for (int k = 0; k < 8; ++k) s += psum[tid + k * 256];
  #pragma unroll
  for (int off = 1; off < 64; off <<= 1) s += __shfl_xor(s, off, 64);
  __shared__ float sr[4];
  if ((tid & 63) == 0) sr[tid >> 6] = s;
  __syncthreads();
  if (tid == 0) scal[0] = 1.f / (sr[0] + sr[1] + sr[2] + sr[3]);
}

__global__ __launch_bounds__(256) void k_norm(const float* __restrict__ eL,
                                              const float* __restrict__ scal,
                                              float* __restrict__ out)
{
  const float inv = scal[0];
  const int i = blockIdx.x * 256 + threadIdx.x;
  if (i < NN / 4) {
    float4 v = ((const float4*)eL)[i];
    float4 o = {v.x * inv, v.y * inv, v.z * inv, v.w * inv};
    ((float4*)out)[i] = o;
  }
}

extern "C" void kernel_launch(void* const* d_in, const int* in_sizes, int n_in,
                              void* d_out, int out_size, void* d_ws, size_t ws_size,
                              hipStream_t stream) {
  const float* enc = (const float*)d_in[0];
  const int*   cs  = (const int*)d_in[1];
  const float* W1  = (const float*)d_in[2];
  const float* b1  = (const float*)d_in[3];
  const float* W2  = (const float*)d_in[4];
  const float* b2  = (const float*)d_in[5];
  const float* W3  = (const float*)d_in[6];
  const float* b3  = (const float*)d_in[7];
  const float* W4  = (const float*)d_in[8];
  const float* b4  = (const float*)d_in[9];
  float* out = (float*)d_out;

  char* ws = (char*)d_ws;
  float* mu_in  = (float*)(ws + 0);        // 512 B
  float* mu_not = (float*)(ws + 512);      // 512 B
  float* cvec   = (float*)(ws + 1024);     // 1 KB
  float* psum   = (float*)(ws + 2048);     // 2048 floats = 8 KB
  float* scal   = (float*)(ws + 10240);    // 4 B
  float* eLbuf  = (float*)(ws + 12288);    // 2 MB (exp(logit) per row)

  hipMemsetAsync(ws, 0, 1024, stream);  // zero mu_in/mu_not (identity for max >= 0)

  k_colmax<<<dim3(1954), dim3(256), 0, stream>>>(enc, cs, mu_in, mu_not);
  k_cvec<<<dim3(1), dim3(512), 0, stream>>>(W1, b1, mu_in, mu_not, cvec);
  k_mlp<<<dim3(256), dim3(512), 0, stream>>>(enc, W1, W2, W3, cvec, b2, b3,
                                             W4, b4, eLbuf, psum);
  k_finalsum<<<dim3(1), dim3(256), 0, stream>>>(psum, scal);
  k_norm<<<dim3(489), dim3(256), 0, stream>>>(eLbuf, scal, out);
}

// Round 3
// 796.473 us; speedup vs baseline: 1.5565x; 1.5565x over previous
//
#include <hip/hip_runtime.h>
#include <hip/hip_bf16.h>

#define NN 500000
// feats = [mu_in(128) | mu_not(128) | enc(128)]; H1=256, H2=128, H3=64

typedef unsigned short ushort_t;
typedef __attribute__((ext_vector_type(8))) __bf16 bf16x8;
typedef __attribute__((ext_vector_type(2))) __bf16 bf16x2;
typedef __attribute__((ext_vector_type(4))) float f32x4;

__device__ inline ushort_t f2bf(float f) {
  union { float f; unsigned u; } x; x.f = f;
  return (ushort_t)((x.u + 0x7FFFu + ((x.u >> 16) & 1u)) >> 16);
}
__device__ inline float lrelu(float v) { return fmaxf(v, 0.f) + 0.01f * fminf(v, 0.f); }
__device__ inline unsigned pk2(float lo, float hi) {
  union { bf16x2 v; unsigned u; } x; x.v[0] = (__bf16)lo; x.v[1] = (__bf16)hi; return x.u;
}
#define SHF(v, s) ((unsigned)__shfl((int)(v), (s), 64))

// ---------------- K_colmax: masked per-column max over N rows ----------------
__global__ __launch_bounds__(256) void k_colmax(
    const float* __restrict__ enc, const int* __restrict__ cs,
    float* mu_in, float* mu_not)
{
  __shared__ float4 s_in[256], s_not[256];
  const int tid = threadIdx.x;
  const int c4 = tid & 31;    // float4-column 0..31
  const int rs = tid >> 5;    // row slice 0..7
  const long base = (long)blockIdx.x * 256;
  float4 mi = {0.f, 0.f, 0.f, 0.f}, mn = {0.f, 0.f, 0.f, 0.f};
  const float4* e4 = (const float4*)enc;
  #pragma unroll 4
  for (int it = 0; it < 32; ++it) {
    long r = base + rs + 8L * it;
    if (r < NN) {
      float4 v = e4[r * 32 + c4];
      bool ins = cs[r] > 0;
      mi.x = fmaxf(mi.x, ins ? v.x : 0.f); mi.y = fmaxf(mi.y, ins ? v.y : 0.f);
      mi.z = fmaxf(mi.z, ins ? v.z : 0.f); mi.w = fmaxf(mi.w, ins ? v.w : 0.f);
      mn.x = fmaxf(mn.x, ins ? 0.f : v.x); mn.y = fmaxf(mn.y, ins ? 0.f : v.y);
      mn.z = fmaxf(mn.z, ins ? 0.f : v.z); mn.w = fmaxf(mn.w, ins ? 0.f : v.w);
    }
  }
  s_in[tid] = mi; s_not[tid] = mn;
  __syncthreads();
  if (tid < 32) {
    for (int j = 1; j < 8; ++j) {
      float4 a = s_in[j * 32 + tid], b = s_not[j * 32 + tid];
      mi.x = fmaxf(mi.x, a.x); mi.y = fmaxf(mi.y, a.y);
      mi.z = fmaxf(mi.z, a.z); mi.w = fmaxf(mi.w, a.w);
      mn.x = fmaxf(mn.x, b.x); mn.y = fmaxf(mn.y, b.y);
      mn.z = fmaxf(mn.z, b.z); mn.w = fmaxf(mn.w, b.w);
    }
    // maxima are >= 0 so int-bit compare == float compare
    atomicMax((int*)&mu_in[4 * tid + 0], __float_as_int(mi.x));
    atomicMax((int*)&mu_in[4 * tid + 1], __float_as_int(mi.y));
    atomicMax((int*)&mu_in[4 * tid + 2], __float_as_int(mi.z));
    atomicMax((int*)&mu_in[4 * tid + 3], __float_as_int(mi.w));
    atomicMax((int*)&mu_not[4 * tid + 0], __float_as_int(mn.x));
    atomicMax((int*)&mu_not[4 * tid + 1], __float_as_int(mn.y));
    atomicMax((int*)&mu_not[4 * tid + 2], __float_as_int(mn.z));
    atomicMax((int*)&mu_not[4 * tid + 3], __float_as_int(mn.w));
  }
}

// ---------------- K_mlp: persistent, weights LDS-resident, barrier-free loop -------------
// 32 rows / wave-iteration (two 16-row groups share every weight ds_read).
// Orientation: A = weights [n_out][k] (LDS), B = activations^T (row index in n slot).
// Layer handoff = 4-lane butterfly shuffles. __launch_bounds__(512,2) -> 256-VGPR cap
// (round-2 failure mode was spill at a 128-VGPR allocation).
__global__ __launch_bounds__(512, 2) void k_mlp(
    const float* __restrict__ enc,
    const float* __restrict__ W1, const float* __restrict__ b1,
    const float* __restrict__ W2, const float* __restrict__ b2,
    const float* __restrict__ W3, const float* __restrict__ b3,
    const float* __restrict__ W4, const float* __restrict__ b4,
    const float* __restrict__ mu_in, const float* __restrict__ mu_not,
    float* __restrict__ eL, float* __restrict__ psum)
{
  __shared__ ushort_t sW1[256 * 136];   // [n1][k=e]   69632 B
  __shared__ ushort_t sW2[128 * 264];   // [n2][k=n1]  67584 B
  __shared__ ushort_t sW3[64 * 136];    // [n3][k=n2]  17408 B
  __shared__ float sC[520];             // c[256]|b2[128]|b3[64]|W4[64]|b4
  __shared__ float sT[512];             // cvec partials

  const int tid = threadIdx.x;

  // ---- one-time staging: fp32 global -> bf16 LDS (transposed) ----
  for (int idx = tid; idx < 32768; idx += 512) {
    int n = idx & 255, k = idx >> 8;              // n1, e
    sW1[n * 136 + k] = f2bf(W1[(256 + k) * 256 + n]);
  }
  for (int idx = tid; idx < 32768; idx += 512) {
    int n = idx & 127, k = idx >> 7;              // n2, n1
    sW2[n * 264 + k] = f2bf(W2[k * 128 + n]);
  }
  for (int idx = tid; idx < 8192; idx += 512) {
    int n = idx & 63, k = idx >> 6;               // n3, n2
    sW3[n * 136 + k] = f2bf(W3[k * 64 + n]);
  }
  if (tid >= 256 && tid < 384) sC[tid] = b2[tid - 256];
  else if (tid >= 384 && tid < 448) sC[tid] = b3[tid - 384];
  else if (tid >= 448) sC[tid] = W4[tid - 448];
  if (tid == 0) sC[512] = b4[0];
  { // inlined cvec: c[j] = b1[j] + mu_in . W1[0:128,j] + mu_not . W1[128:256,j]
    const int j = tid & 255, h = tid >> 8;
    float c = h ? 0.f : b1[j];
    #pragma unroll 8
    for (int e = 64 * h; e < 64 * h + 64; ++e) {
      c += mu_in[e]  * W1[e * 256 + j];
      c += mu_not[e] * W1[(128 + e) * 256 + j];
    }
    sT[tid] = c;
  }
  __syncthreads();
  if (tid < 256) sC[tid] = sT[tid] + sT[tid + 256];
  __syncthreads();   // last block-wide barrier

  const int wave = tid >> 6, lane = tid & 63;
  const int lr = lane & 15, lg = lane >> 4;
  const int wid = blockIdx.x * 8 + wave;          // 0..2047
  const int selhi = lane & 32;
  const int srcLo = lr + ((lane & 16) << 1);      // butterfly partner lanes
  const int srcHi = srcLo + 16;

  const ushort_t* w1p = sW1 + lr * 136 + 8 * lg;  // + mt*2176 + kt*32
  const ushort_t* w2p = sW2 + lr * 264 + 8 * lg;  // + mt*4224 + kt*32
  const ushort_t* w3p = sW3 + lr * 136 + 8 * lg;

  float es = 0.f;
  bf16x8 B1a[4], B1b[4];

  // preload + convert first 32-row group (NN = 32*15625, no tails ever)
  {
    const float4* pa = (const float4*)(enc + (size_t)(wid * 32 + lr) * 128);
    const float4* pb = (const float4*)(enc + (size_t)(wid * 32 + 16 + lr) * 128);
    #pragma unroll
    for (int kt = 0; kt < 4; ++kt) {
      float4 f0 = pa[kt * 8 + lg * 2], f1 = pa[kt * 8 + lg * 2 + 1];
      float4 g0 = pb[kt * 8 + lg * 2], g1 = pb[kt * 8 + lg * 2 + 1];
      bf16x8 a, b;
      a[0] = (__bf16)f0.x; a[1] = (__bf16)f0.y; a[2] = (__bf16)f0.z; a[3] = (__bf16)f0.w;
      a[4] = (__bf16)f1.x; a[5] = (__bf16)f1.y; a[6] = (__bf16)f1.z; a[7] = (__bf16)f1.w;
      b[0] = (__bf16)g0.x; b[1] = (__bf16)g0.y; b[2] = (__bf16)g0.z; b[3] = (__bf16)g0.w;
      b[4] = (__bf16)g1.x; b[5] = (__bf16)g1.y; b[6] = (__bf16)g1.z; b[7] = (__bf16)g1.w;
      B1a[kt] = a; B1b[kt] = b;
    }
  }

  for (int r0 = wid * 32; r0 < NN; r0 += 65536) {
    // ---- L1: acc[n1-tile][rows]; each weight frag feeds both row groups ----
    f32x4 accA[16], accB[16];
    #pragma unroll
    for (int mt = 0; mt < 16; ++mt) {
      accA[mt] = (f32x4){0.f, 0.f, 0.f, 0.f};
      accB[mt] = (f32x4){0.f, 0.f, 0.f, 0.f};
    }
    #pragma unroll
    for (int kt = 0; kt < 4; ++kt) {
      #pragma unroll
      for (int mt = 0; mt < 16; ++mt) {
        bf16x8 a = *(const bf16x8*)(w1p + mt * 2176 + kt * 32);
        accA[mt] = __builtin_amdgcn_mfma_f32_16x16x32_bf16(a, B1a[kt], accA[mt], 0, 0, 0);
        accB[mt] = __builtin_amdgcn_mfma_f32_16x16x32_bf16(a, B1b[kt], accB[mt], 0, 0, 0);
      }
    }
    // ---- prefetch next 32-row group (consumed at loop bottom, ~1400 cyc away) ----
    int rn = r0 + 65536; if (rn >= NN) rn = r0;   // last iter: dummy reload
    float4 tA[8], tB[8];
    {
      const float4* pa = (const float4*)(enc + (size_t)(rn + lr) * 128);
      const float4* pb = (const float4*)(enc + (size_t)(rn + 16 + lr) * 128);
      #pragma unroll
      for (int kt = 0; kt < 4; ++kt) {
        tA[2 * kt]     = pa[kt * 8 + lg * 2];
        tA[2 * kt + 1] = pa[kt * 8 + lg * 2 + 1];
        tB[2 * kt]     = pb[kt * 8 + lg * 2];
        tB[2 * kt + 1] = pb[kt * 8 + lg * 2 + 1];
      }
    }
    // ---- L1 epilogue group a: +c, lrelu, pack, butterfly -> B2a ----
    bf16x8 B2a[8], B2b[8];
    {
      unsigned q1[32];
      #pragma unroll
      for (int mt = 0; mt < 16; ++mt) {
        float4 cb = *(const float4*)(sC + 16 * mt + 4 * lg);
        float v0 = lrelu(accA[mt][0] + cb.x), v1 = lrelu(accA[mt][1] + cb.y);
        float v2 = lrelu(accA[mt][2] + cb.z), v3 = lrelu(accA[mt][3] + cb.w);
        q1[2 * mt] = pk2(v0, v1); q1[2 * mt + 1] = pk2(v2, v3);
      }
      #pragma unroll
      for (int kt = 0; kt < 8; ++kt) {
        unsigned w0a = SHF(q1[4 * kt + 0], srcLo), w0b = SHF(q1[4 * kt + 2], srcLo);
        unsigned w1a = SHF(q1[4 * kt + 1], srcLo), w1b = SHF(q1[4 * kt + 3], srcLo);
        unsigned w2a = SHF(q1[4 * kt + 0], srcHi), w2b = SHF(q1[4 * kt + 2], srcHi);
        unsigned w3a = SHF(q1[4 * kt + 1], srcHi), w3b = SHF(q1[4 * kt + 3], srcHi);
        union { unsigned w[4]; bf16x8 v; } u;
        u.w[0] = selhi ? w0b : w0a; u.w[1] = selhi ? w1b : w1a;
        u.w[2] = selhi ? w2b : w2a; u.w[3] = selhi ? w3b : w3a;
        B2a[kt] = u.v;
      }
    }
    // ---- L1 epilogue group b ----
    {
      unsigned q1[32];
      #pragma unroll
      for (int mt = 0; mt < 16; ++mt) {
        float4 cb = *(const float4*)(sC + 16 * mt + 4 * lg);
        float v0 = lrelu(accB[mt][0] + cb.x), v1 = lrelu(accB[mt][1] + cb.y);
        float v2 = lrelu(accB[mt][2] + cb.z), v3 = lrelu(accB[mt][3] + cb.w);
        q1[2 * mt] = pk2(v0, v1); q1[2 * mt + 1] = pk2(v2, v3);
      }
      #pragma unroll
      for (int kt = 0; kt < 8; ++kt) {
        unsigned w0a = SHF(q1[4 * kt + 0], srcLo), w0b = SHF(q1[4 * kt + 2], srcLo);
        unsigned w1a = SHF(q1[4 * kt + 1], srcLo), w1b = SHF(q1[4 * kt + 3], srcLo);
        unsigned w2a = SHF(q1[4 * kt + 0], srcHi), w2b = SHF(q1[4 * kt + 2], srcHi);
        unsigned w3a = SHF(q1[4 * kt + 1], srcHi), w3b = SHF(q1[4 * kt + 3], srcHi);
        union { unsigned w[4]; bf16x8 v; } u;
        u.w[0] = selhi ? w0b : w0a; u.w[1] = selhi ? w1b : w1a;
        u.w[2] = selhi ? w2b : w2a; u.w[3] = selhi ? w3b : w3a;
        B2b[kt] = u.v;
      }
    }
    // ---- L2 ----
    f32x4 acc2A[8], acc2B[8];
    #pragma unroll
    for (int mt = 0; mt < 8; ++mt) {
      acc2A[mt] = (f32x4){0.f, 0.f, 0.f, 0.f};
      acc2B[mt] = (f32x4){0.f, 0.f, 0.f, 0.f};
    }
    #pragma unroll
    for (int kt = 0; kt < 8; ++kt) {
      #pragma unroll
      for (int mt = 0; mt < 8; ++mt) {
        bf16x8 a = *(const bf16x8*)(w2p + mt * 4224 + kt * 32);
        acc2A[mt] = __builtin_amdgcn_mfma_f32_16x16x32_bf16(a, B2a[kt], acc2A[mt], 0, 0, 0);
        acc2B[mt] = __builtin_amdgcn_mfma_f32_16x16x32_bf16(a, B2b[kt], acc2B[mt], 0, 0, 0);
      }
    }
    // ---- L2 epilogue + butterfly -> B3a/B3b ----
    bf16x8 B3a[4], B3b[4];
    {
      unsigned q2[16];
      #pragma unroll
      for (int mt = 0; mt < 8; ++mt) {
        float4 cb = *(const float4*)(sC + 256 + 16 * mt + 4 * lg);
        float v0 = lrelu(acc2A[mt][0] + cb.x), v1 = lrelu(acc2A[mt][1] + cb.y);
        float v2 = lrelu(acc2A[mt][2] + cb.z), v3 = lrelu(acc2A[mt][3] + cb.w);
        q2[2 * mt] = pk2(v0, v1); q2[2 * mt + 1] = pk2(v2, v3);
      }
      #pragma unroll
      for (int kt = 0; kt < 4; ++kt) {
        unsigned w0a = SHF(q2[4 * kt + 0], srcLo), w0b = SHF(q2[4 * kt + 2], srcLo);
        unsigned w1a = SHF(q2[4 * kt + 1], srcLo), w1b = SHF(q2[4 * kt + 3], srcLo);
        unsigned w2a = SHF(q2[4 * kt + 0], srcHi), w2b = SHF(q2[4 * kt + 2], srcHi);
        unsigned w3a = SHF(q2[4 * kt + 1], srcHi), w3b = SHF(q2[4 * kt + 3], srcHi);
        union { unsigned w[4]; bf16x8 v; } u;
        u.w[0] = selhi ? w0b : w0a; u.w[1] = selhi ? w1b : w1a;
        u.w[2] = selhi ? w2b : w2a; u.w[3] = selhi ? w3b : w3a;
        B3a[kt] = u.v;
      }
    }
    {
      unsigned q2[16];
      #pragma unroll
      for (int mt = 0; mt < 8; ++mt) {
        float4 cb = *(const float4*)(sC + 256 + 16 * mt + 4 * lg);
        float v0 = lrelu(acc2B[mt][0] + cb.x), v1 = lrelu(acc2B[mt][1] + cb.y);
        float v2 = lrelu(acc2B[mt][2] + cb.z), v3 = lrelu(acc2B[mt][3] + cb.w);
        q2[2 * mt] = pk2(v0, v1); q2[2 * mt + 1] = pk2(v2, v3);
      }
      #pragma unroll
      for (int kt = 0; kt < 4; ++kt) {
        unsigned w0a = SHF(q2[4 * kt + 0], srcLo), w0b = SHF(q2[4 * kt + 2], srcLo);
        unsigned w1a = SHF(q2[4 * kt + 1], srcLo), w1b = SHF(q2[4 * kt + 3], srcLo);
        unsigned w2a = SHF(q2[4 * kt + 0], srcHi), w2b = SHF(q2[4 * kt + 2], srcHi);
        unsigned w3a = SHF(q2[4 * kt + 1], srcHi), w3b = SHF(q2[4 * kt + 3], srcHi);
        union { unsigned w[4]; bf16x8 v; } u;
        u.w[0] = selhi ? w0b : w0a; u.w[1] = selhi ? w1b : w1a;
        u.w[2] = selhi ? w2b : w2a; u.w[3] = selhi ? w3b : w3a;
        B3b[kt] = u.v;
      }
    }
    // ---- L3 ----
    f32x4 acc3A[4], acc3B[4];
    #pragma unroll
    for (int mt = 0; mt < 4; ++mt) {
      acc3A[mt] = (f32x4){0.f, 0.f, 0.f, 0.f};
      acc3B[mt] = (f32x4){0.f, 0.f, 0.f, 0.f};
    }
    #pragma unroll
    for (int kt = 0; kt < 4; ++kt) {
      #pragma unroll
      for (int mt = 0; mt < 4; ++mt) {
        bf16x8 a = *(const bf16x8*)(w3p + mt * 2176 + kt * 32);
        acc3A[mt] = __builtin_amdgcn_mfma_f32_16x16x32_bf16(a, B3a[kt], acc3A[mt], 0, 0, 0);
        acc3B[mt] = __builtin_amdgcn_mfma_f32_16x16x32_bf16(a, B3b[kt], acc3B[mt], 0, 0, 0);
      }
    }
    // ---- L4: +b3, lrelu, dot W4, reduce over lg; exp ----
    float da = 0.f, db = 0.f;
    #pragma unroll
    for (int t = 0; t < 4; ++t) {
      float4 cb  = *(const float4*)(sC + 384 + 16 * t + 4 * lg);
      float4 w4v = *(const float4*)(sC + 448 + 16 * t + 4 * lg);
      da += lrelu(acc3A[t][0] + cb.x) * w4v.x + lrelu(acc3A[t][1] + cb.y) * w4v.y
          + lrelu(acc3A[t][2] + cb.z) * w4v.z + lrelu(acc3A[t][3] + cb.w) * w4v.w;
      db += lrelu(acc3B[t][0] + cb.x) * w4v.x + lrelu(acc3B[t][1] + cb.y) * w4v.y
          + lrelu(acc3B[t][2] + cb.z) * w4v.z + lrelu(acc3B[t][3] + cb.w) * w4v.w;
    }
    da += __shfl_xor(da, 16, 64); da += __shfl_xor(da, 32, 64);
    db += __shfl_xor(db, 16, 64); db += __shfl_xor(db, 32, 64);
    float eva = expf(da + sC[512]), evb = expf(db + sC[512]);
    if (lg == 0) { eL[r0 + lr] = eva; eL[r0 + 16 + lr] = evb; }
    es += eva + evb;                 // 4x duplicated across lg, scaled at the end
    // ---- convert prefetched rows -> B1 for next iteration ----
    #pragma unroll
    for (int kt = 0; kt < 4; ++kt) {
      float4 f0 = tA[2 * kt], f1 = tA[2 * kt + 1];
      float4 g0 = tB[2 * kt], g1 = tB[2 * kt + 1];
      bf16x8 a, b;
      a[0] = (__bf16)f0.x; a[1] = (__bf16)f0.y; a[2] = (__bf16)f0.z; a[3] = (__bf16)f0.w;
      a[4] = (__bf16)f1.x; a[5] = (__bf16)f1.y; a[6] = (__bf16)f1.z; a[7] = (__bf16)f1.w;
      b[0] = (__bf16)g0.x; b[1] = (__bf16)g0.y; b[2] = (__bf16)g0.z; b[3] = (__bf16)g0.w;
      b[4] = (__bf16)g1.x; b[5] = (__bf16)g1.y; b[6] = (__bf16)g1.z; b[7] = (__bf16)g1.w;
      B1a[kt] = a; B1b[kt] = b;
    }
  }
  // wave-wide partial softmax denominator (deterministic: one slot per wave)
  #pragma unroll
  for (int off = 1; off < 64; off <<= 1) es += __shfl_xor(es, off, 64);
  if (lane == 0) psum[wid] = 0.25f * es;
}

// ---------------- final reduce + normalize ----------------
__global__ __launch_bounds__(256) void k_finalsum(const float* __restrict__ psum,
                                                  float* __restrict__ scal)
{
  const int tid = threadIdx.x;
  float s = 0.f;
  #pragma unroll
  for (int k = 0; k < 8; ++k) s += psum[tid + k * 256];
  #pragma unroll
  for (int off = 1; off < 64; off <<= 1) s += __shfl_xor(s, off, 64);
  __shared__ float sr[4];
  if ((tid & 63) == 0) sr[tid >> 6] = s;
  __syncthreads();
  if (tid == 0) scal[0] = 1.f / (sr[0] + sr[1] + sr[2] + sr[3]);
}

__global__ __launch_bounds__(256) void k_norm(const float* __restrict__ eL,
                                              const float* __restrict__ scal,
                                              float* __restrict__ out)
{
  const float inv = scal[0];
  const int i = blockIdx.x * 256 + threadIdx.x;
  if (i < NN / 4) {
    float4 v = ((const float4*)eL)[i];
    float4 o = {v.x * inv, v.y * inv, v.z * inv, v.w * inv};
    ((float4*)out)[i] = o;
  }
}

extern "C" void kernel_launch(void* const* d_in, const int* in_sizes, int n_in,
                              void* d_out, int out_size, void* d_ws, size_t ws_size,
                              hipStream_t stream) {
  const float* enc = (const float*)d_in[0];
  const int*   cs  = (const int*)d_in[1];
  const float* W1  = (const float*)d_in[2];
  const float* b1  = (const float*)d_in[3];
  const float* W2  = (const float*)d_in[4];
  const float* b2  = (const float*)d_in[5];
  const float* W3  = (const float*)d_in[6];
  const float* b3  = (const float*)d_in[7];
  const float* W4  = (const float*)d_in[8];
  const float* b4  = (const float*)d_in[9];
  float* out = (float*)d_out;

  char* ws = (char*)d_ws;
  float* mu_in  = (float*)(ws + 0);        // 512 B
  float* mu_not = (float*)(ws + 512);      // 512 B
  float* psum   = (float*)(ws + 2048);     // 2048 floats = 8 KB
  float* scal   = (float*)(ws + 10240);    // 4 B
  float* eLbuf  = (float*)(ws + 12288);    // 2 MB (exp(logit) per row)

  hipMemsetAsync(ws, 0, 1024, stream);  // zero mu_in/mu_not (identity for max >= 0)

  k_colmax<<<dim3(1954), dim3(256), 0, stream>>>(enc, cs, mu_in, mu_not);
  k_mlp<<<dim3(256), dim3(512), 0, stream>>>(enc, W1, b1, W2, b2, W3, b3, W4, b4,
                                             mu_in, mu_not, eLbuf, psum);
  k_finalsum<<<dim3(1), dim3(256), 0, stream>>>(psum, scal);
  k_norm<<<dim3(489), dim3(256), 0, stream>>>(eLbuf, scal, out);
}